// Round 2
// baseline (454.371 us; speedup 1.0000x reference)
//
#include <hip/hip_runtime.h>

#define NN 1000
#define NE 64000
#define HH 256

typedef _Float16 half8 __attribute__((ext_vector_type(8)));
typedef float floatx4 __attribute__((ext_vector_type(4)));

struct PrepArgs { const float* w0[5]; const float* w1[5]; };

// Rearrange weights to fp16:
//  wnode[l]: [512][256] rows 0..255 = (A - B), rows 256..511 = B   (A=w0[:, :D], B=w0[:, D:])
//  w2h[l]:   [256][256] = w1 cast
__global__ void prep_weights(PrepArgs pa, _Float16* wnode, _Float16* w2h) {
    int l = blockIdx.y;
    int D = l ? 256 : 128;
    const float* w0 = pa.w0[l];
    const float* w1 = pa.w1[l];
    _Float16* wn = wnode + (size_t)l * 512 * 256;
    _Float16* w2 = w2h + (size_t)l * 256 * 256;
    int stride = gridDim.x * blockDim.x;
    for (int i = blockIdx.x * blockDim.x + threadIdx.x; i < 512 * D; i += stride) {
        int n = i / D, k = i - n * D;
        float v = (n < 256) ? (w0[n * 2 * D + k] - w0[n * 2 * D + D + k])
                            : w0[(n - 256) * 2 * D + D + k];
        wn[n * 256 + k] = (_Float16)v;
    }
    for (int i = blockIdx.x * blockDim.x + threadIdx.x; i < 256 * 256; i += stride)
        w2[i] = (_Float16)w1[i];
}

// edge_index arrives as int32 (harness converts integer inputs to int): [2][NE]
__global__ void hist_kernel(const int* __restrict__ ei, int* __restrict__ counts) {
    int e = blockIdx.x * blockDim.x + threadIdx.x;
    if (e < NE) {
        int d = ei[NE + e];
        atomicAdd(&counts[d & 1023], 1);
    }
}

__global__ void scan_kernel(const int* __restrict__ counts, int* __restrict__ cursor) {
    __shared__ int s[1024];
    int t = threadIdx.x;
    int c = (t < NN) ? counts[t] : 0;
    s[t] = c;
    __syncthreads();
    for (int d = 1; d < 1024; d <<= 1) {
        int v = 0;
        if (t >= d) v = s[t - d];
        __syncthreads();
        s[t] += v;
        __syncthreads();
    }
    cursor[t] = s[t] - c;  // exclusive prefix
}

__global__ void scatter_kernel(const int* __restrict__ ei, int* __restrict__ cursor,
                               int* __restrict__ ssrc, int* __restrict__ sdst) {
    int e = blockIdx.x * blockDim.x + threadIdx.x;
    if (e < NE) {
        int s = ei[e] & 1023, d = ei[NE + e] & 1023;
        int pos = atomicAdd(&cursor[d], 1);
        if (pos < NE) {
            ssrc[pos] = s;
            sdst[pos] = d;
        }
    }
}

__global__ void zero_kernel(float* __restrict__ p, int n) {
    int i = blockIdx.x * blockDim.x + threadIdx.x;
    if (i < n) p[i] = 0.f;
}

// out[node][0:256] = a = X@(A-B)^T + b0 ; out[node][256:512] = b = X@B^T
// C = X[M,K] @ Wn[512,K]^T ; M=1000 (grid.x=16 m-tiles), N=512 (grid.y=2), wave gets 64 cols
__launch_bounds__(256)
__global__ void node_gemm(const float* __restrict__ X, int Kd,
                          const _Float16* __restrict__ Wn, const float* __restrict__ b0,
                          _Float16* __restrict__ out) {
    int wave = threadIdx.x >> 6, lane = threadIdx.x & 63;
    int q = lane >> 4, mn = lane & 15;
    int m0 = blockIdx.x * 64;
    int n0 = blockIdx.y * 256 + wave * 64;
    floatx4 acc[4][4] = {};
    for (int k0 = 0; k0 < Kd; k0 += 32) {
        int ka = k0 + q * 8;
        half8 af[4], bf[4];
#pragma unroll
        for (int mt = 0; mt < 4; mt++) {
            int row = m0 + mt * 16 + mn;
            if (row >= NN) row = NN - 1;
            const float* p = X + (size_t)row * Kd + ka;
            floatx4 x0 = *(const floatx4*)p;
            floatx4 x1 = *(const floatx4*)(p + 4);
            half8 a;
            a[0] = (_Float16)x0[0]; a[1] = (_Float16)x0[1];
            a[2] = (_Float16)x0[2]; a[3] = (_Float16)x0[3];
            a[4] = (_Float16)x1[0]; a[5] = (_Float16)x1[1];
            a[6] = (_Float16)x1[2]; a[7] = (_Float16)x1[3];
            af[mt] = a;
        }
#pragma unroll
        for (int nt = 0; nt < 4; nt++)
            bf[nt] = *(const half8*)(Wn + (size_t)(n0 + nt * 16 + mn) * 256 + ka);
#pragma unroll
        for (int mt = 0; mt < 4; mt++)
#pragma unroll
            for (int nt = 0; nt < 4; nt++)
                acc[mt][nt] = __builtin_amdgcn_mfma_f32_16x16x32_f16(af[mt], bf[nt], acc[mt][nt], 0, 0, 0);
    }
#pragma unroll
    for (int mt = 0; mt < 4; mt++)
#pragma unroll
        for (int nt = 0; nt < 4; nt++) {
            int col = n0 + nt * 16 + mn;
            float bias = (col < 256) ? b0[col] : 0.f;
#pragma unroll
            for (int r2 = 0; r2 < 4; r2++) {
                int row = m0 + mt * 16 + q * 4 + r2;
                if (row < NN)
                    out[(size_t)row * 512 + col] = (_Float16)(acc[mt][nt][r2] + bias);
            }
        }
}

// Per-edge: h1 = relu(a[dst] + b[src]) [64 edges x 256] in LDS; C = h1 @ W2^T + b2;
// clamp>=0; merge consecutive same-dst rows in-register; atomicMax(uint) into agg.
__launch_bounds__(256)
__global__ void edge_gemm(const _Float16* __restrict__ node_ab,
                          const int* __restrict__ ssrc, const int* __restrict__ sdst,
                          const _Float16* __restrict__ W2, const float* __restrict__ b2,
                          float* __restrict__ agg) {
    __shared__ _Float16 h1[64][264];  // pad 264: breaks power-of-2 row stride
    __shared__ int sd[64];
    int t = threadIdx.x;
    int e0 = blockIdx.x * 64;
    if (t < 64) sd[t] = sdst[e0 + t];
    {
        int w = t >> 6, l6 = t & 63;
        int row = w * 16 + (l6 >> 2);
        int p = l6 & 3;
        int dn = sdst[e0 + row], sn = ssrc[e0 + row];
        const _Float16* pa = node_ab + (size_t)dn * 512;
        const _Float16* pb = node_ab + (size_t)sn * 512 + 256;
#pragma unroll
        for (int i = 0; i < 8; i++) {
            int c = (p + i * 4) * 8;
            half8 av = *(const half8*)(pa + c);
            half8 bv = *(const half8*)(pb + c);
            half8 hv;
#pragma unroll
            for (int j = 0; j < 8; j++) {
                _Float16 s = (_Float16)(av[j] + bv[j]);
                hv[j] = s > (_Float16)0 ? s : (_Float16)0;
            }
            *(half8*)(&h1[row][c]) = hv;
        }
    }
    __syncthreads();

    int wave = t >> 6, lane = t & 63;
    int q = lane >> 4, mn = lane & 15;
    int n0 = wave * 64;
    floatx4 acc[4][4] = {};
#pragma unroll
    for (int k0 = 0; k0 < 256; k0 += 32) {
        half8 af[4], bf[4];
#pragma unroll
        for (int mt = 0; mt < 4; mt++)
            af[mt] = *(const half8*)(&h1[mt * 16 + mn][k0 + q * 8]);
#pragma unroll
        for (int nt = 0; nt < 4; nt++)
            bf[nt] = *(const half8*)(W2 + (size_t)(n0 + nt * 16 + mn) * 256 + k0 + q * 8);
#pragma unroll
        for (int mt = 0; mt < 4; mt++)
#pragma unroll
            for (int nt = 0; nt < 4; nt++)
                acc[mt][nt] = __builtin_amdgcn_mfma_f32_16x16x32_f16(af[mt], bf[nt], acc[mt][nt], 0, 0, 0);
    }

#pragma unroll
    for (int nt = 0; nt < 4; nt++) {
        int col = n0 + nt * 16 + mn;
        float bias = b2[col];
        int curd = -1;
        float curv = 0.f;
#pragma unroll
        for (int mt = 0; mt < 4; mt++) {
#pragma unroll
            for (int r2 = 0; r2 < 4; r2++) {
                int er = mt * 16 + q * 4 + r2;  // monotone in (mt,r2) -> sorted dst runs merge
                int d = sd[er];
                float v = acc[mt][nt][r2] + bias;
                v = v > 0.f ? v : 0.f;
                if (d != curd) {
                    if (curd >= 0 && curv > 0.f)
                        atomicMax((unsigned int*)(agg + (size_t)curd * HH + col), __float_as_uint(curv));
                    curd = d;
                    curv = v;
                } else {
                    curv = fmaxf(curv, v);
                }
            }
        }
        if (curd >= 0 && curv > 0.f)
            atomicMax((unsigned int*)(agg + (size_t)curd * HH + col), __float_as_uint(curv));
    }
}

extern "C" void kernel_launch(void* const* d_in, const int* in_sizes, int n_in,
                              void* d_out, int out_size, void* d_ws, size_t ws_size,
                              hipStream_t stream) {
    const float* x = (const float*)d_in[0];
    const int* ei = (const int*)d_in[1];  // int32 per harness contract
    PrepArgs pa;
    const float* b0s[5];
    const float* b1s[5];
    for (int l = 0; l < 5; l++) {
        pa.w0[l] = (const float*)d_in[2 + 4 * l];
        b0s[l] = (const float*)d_in[3 + 4 * l];
        pa.w1[l] = (const float*)d_in[4 + 4 * l];
        b1s[l] = (const float*)d_in[5 + 4 * l];
    }

    int* ssrc = (int*)d_ws;                              // 256 KB
    int* sdst = ssrc + NE;                               // 256 KB
    int* counts = sdst + NE;                             // 4 KB
    int* cursor = counts + 1024;                         // 4 KB
    _Float16* node_ab = (_Float16*)(cursor + 1024);      // [1024][512] fp16, 1 MB
    float* aggA = (float*)(node_ab + 1024 * 512);        // [1000][256] fp32, 1 MB
    _Float16* wnode = (_Float16*)(aggA + NN * HH);       // 5 x [512][256] fp16, 1.25 MB
    _Float16* w2h = wnode + 5 * 512 * 256;               // 5 x [256][256] fp16, 0.63 MB

    hipLaunchKernelGGL(zero_kernel, dim3(4), dim3(256), 0, stream, (float*)counts, 1024);
    hipLaunchKernelGGL(hist_kernel, dim3((NE + 255) / 256), dim3(256), 0, stream, ei, counts);
    hipLaunchKernelGGL(scan_kernel, dim3(1), dim3(1024), 0, stream, counts, cursor);
    hipLaunchKernelGGL(scatter_kernel, dim3((NE + 255) / 256), dim3(256), 0, stream, ei, cursor, ssrc, sdst);
    hipLaunchKernelGGL(prep_weights, dim3(32, 5), dim3(256), 0, stream, pa, wnode, w2h);

    const float* cur = x;
    int D = 128;
    // Layers 0-3 write aggA, layer 4 writes d_out. Reusing aggA as both input
    // and output of a layer is safe: node_gemm fully consumes it before the
    // zero+edge_gemm pair clobbers it (stream-ordered).
    float* aggs[5] = {aggA, aggA, aggA, aggA, (float*)d_out};
    for (int l = 0; l < 5; l++) {
        hipLaunchKernelGGL(node_gemm, dim3(16, 2), dim3(256), 0, stream,
                           cur, D, wnode + (size_t)l * 512 * 256, b0s[l], node_ab);
        hipLaunchKernelGGL(zero_kernel, dim3((NN * HH + 255) / 256), dim3(256), 0, stream,
                           aggs[l], NN * HH);
        hipLaunchKernelGGL(edge_gemm, dim3(NE / 64), dim3(256), 0, stream,
                           node_ab, ssrc, sdst, w2h + (size_t)l * 256 * 256, b1s[l], aggs[l]);
        cur = aggs[l];
        D = 256;
    }
}

// Round 3
// 343.970 us; speedup vs baseline: 1.3210x; 1.3210x over previous
//
#include <hip/hip_runtime.h>

#define NN 1000
#define NE 64000
#define HH 256

typedef _Float16 half8 __attribute__((ext_vector_type(8)));
typedef float floatx4 __attribute__((ext_vector_type(4)));

struct PrepArgs { const float* w0[5]; const float* w1[5]; };

// wnode[l]: [512][256] rows 0..255 = (A - B), rows 256..511 = B   (A=w0[:, :D], B=w0[:, D:])
// w2h[l]:   [256][256] = w1 cast to fp16
__global__ void prep_weights(PrepArgs pa, _Float16* wnode, _Float16* w2h) {
    int l = blockIdx.y;
    int D = l ? 256 : 128;
    const float* w0 = pa.w0[l];
    const float* w1 = pa.w1[l];
    _Float16* wn = wnode + (size_t)l * 512 * 256;
    _Float16* w2 = w2h + (size_t)l * 256 * 256;
    int stride = gridDim.x * blockDim.x;
    for (int i = blockIdx.x * blockDim.x + threadIdx.x; i < 512 * D; i += stride) {
        int n = i / D, k = i - n * D;
        float v = (n < 256) ? (w0[n * 2 * D + k] - w0[n * 2 * D + D + k])
                            : w0[(n - 256) * 2 * D + D + k];
        wn[n * 256 + k] = (_Float16)v;
    }
    for (int i = blockIdx.x * blockDim.x + threadIdx.x; i < 256 * 256; i += stride)
        w2[i] = (_Float16)w1[i];
}

__global__ void hist_kernel(const int* __restrict__ ei, int* __restrict__ counts) {
    int e = blockIdx.x * blockDim.x + threadIdx.x;
    if (e < NE) atomicAdd(&counts[ei[NE + e] & 1023], 1);
}

__global__ void scan_kernel(const int* __restrict__ counts, int* __restrict__ cursor) {
    __shared__ int s[1024];
    int t = threadIdx.x;
    int c = (t < NN) ? counts[t] : 0;
    s[t] = c;
    __syncthreads();
    for (int d = 1; d < 1024; d <<= 1) {
        int v = 0;
        if (t >= d) v = s[t - d];
        __syncthreads();
        s[t] += v;
        __syncthreads();
    }
    cursor[t] = s[t] - c;  // exclusive prefix
}

__global__ void scatter_kernel(const int* __restrict__ ei, int* __restrict__ cursor,
                               int* __restrict__ ssrc, int* __restrict__ sdst) {
    int e = blockIdx.x * blockDim.x + threadIdx.x;
    if (e < NE) {
        int s = ei[e] & 1023, d = ei[NE + e] & 1023;
        int pos = atomicAdd(&cursor[d], 1);
        if (pos < NE) {
            ssrc[pos] = s;
            sdst[pos] = d;
        }
    }
}

// C = X[M,Kd] @ Wn[512,Kd]^T. Tile: 16 rows x 128 cols per block (wave: 16x32).
// All loads hoisted into register arrays (NK=4 or 8) -> one latency exposure.
template <int NK>
__launch_bounds__(256)
__global__ void node_gemm(const float* __restrict__ X,
                          const _Float16* __restrict__ Wn, const float* __restrict__ b0,
                          _Float16* __restrict__ out) {
    const int Kd = NK * 32;
    int wave = threadIdx.x >> 6, lane = threadIdx.x & 63;
    int q = lane >> 4, mn = lane & 15;
    int m0 = blockIdx.x * 16;
    int n0 = blockIdx.y * 128 + wave * 32;
    int rr = m0 + mn;
    if (rr >= NN) rr = NN - 1;

    half8 afa[NK];
    half8 bfa[NK][2];
#pragma unroll
    for (int kk = 0; kk < NK; kk++) {
        int ka = kk * 32 + q * 8;
        const float* p = X + (size_t)rr * Kd + ka;
        floatx4 x0 = *(const floatx4*)p;
        floatx4 x1 = *(const floatx4*)(p + 4);
        half8 a;
#pragma unroll
        for (int j = 0; j < 4; j++) { a[j] = (_Float16)x0[j]; a[4 + j] = (_Float16)x1[j]; }
        afa[kk] = a;
        bfa[kk][0] = *(const half8*)(Wn + (size_t)(n0 + mn) * 256 + ka);
        bfa[kk][1] = *(const half8*)(Wn + (size_t)(n0 + 16 + mn) * 256 + ka);
    }
    floatx4 acc[2] = {};
#pragma unroll
    for (int kk = 0; kk < NK; kk++) {
        acc[0] = __builtin_amdgcn_mfma_f32_16x16x32_f16(afa[kk], bfa[kk][0], acc[0], 0, 0, 0);
        acc[1] = __builtin_amdgcn_mfma_f32_16x16x32_f16(afa[kk], bfa[kk][1], acc[1], 0, 0, 0);
    }
#pragma unroll
    for (int nt = 0; nt < 2; nt++) {
        int col = n0 + nt * 16 + mn;
        float bias = (col < 256) ? b0[col] : 0.f;
#pragma unroll
        for (int r2 = 0; r2 < 4; r2++) {
            int orow = m0 + q * 4 + r2;
            if (orow < NN)
                out[(size_t)orow * 512 + col] = (_Float16)(acc[nt][r2] + bias);
        }
    }
}

// Per-edge MLP layer 2 + scatter-max. Block: 64 sorted edges x 256 cols, 4 waves.
// h1 = relu(a[dst]+b[src]) staged in XOR-swizzled LDS (conflict-free b128);
// K-loop: 1-deep register prefetch of W2 fragments; epilogue merges same-dst
// runs in-register then atomicMax(uint) (values clamped >= 0, agg zero-init).
__launch_bounds__(256)
__global__ void edge_gemm(const _Float16* __restrict__ node_ab,
                          const int* __restrict__ ssrc, const int* __restrict__ sdst,
                          const _Float16* __restrict__ W2, const float* __restrict__ b2,
                          float* __restrict__ agg) {
    __shared__ _Float16 h1[64 * 256];
    __shared__ int sd[64];
    int t = threadIdx.x;
    int e0 = blockIdx.x * 64;
    int wave = t >> 6, lane = t & 63;
    int q = lane >> 4, mn = lane & 15;
    int n0 = wave * 64;

    // issue first B-fragment loads early: latency hides under staging+barrier
    half8 bf_cur[4], bf_nxt[4];
#pragma unroll
    for (int nt = 0; nt < 4; nt++)
        bf_cur[nt] = *(const half8*)(W2 + (size_t)(n0 + nt * 16 + mn) * 256 + q * 8);

    if (t < 64) sd[t] = sdst[e0 + t];

    {   // staging: thread -> row t&63, 8 contiguous 16B chunks; all 16 loads in flight
        int row = t & 63;
        int cb = (t >> 6) * 8;
        int dn = sdst[e0 + row], sn = ssrc[e0 + row];
        const _Float16* pa = node_ab + (size_t)dn * 512 + cb * 8;
        const _Float16* pb = node_ab + (size_t)sn * 512 + 256 + cb * 8;
        half8 av[8], bv[8];
#pragma unroll
        for (int i = 0; i < 8; i++) av[i] = *(const half8*)(pa + i * 8);
#pragma unroll
        for (int i = 0; i < 8; i++) bv[i] = *(const half8*)(pb + i * 8);
#pragma unroll
        for (int i = 0; i < 8; i++) {
            int c = cb + i;
            int p = (c & ~7) | ((c ^ row) & 7);  // XOR swizzle: conflict-free b128
            half8 hv = av[i] + bv[i];
#pragma unroll
            for (int j = 0; j < 8; j++) hv[j] = hv[j] > (_Float16)0 ? hv[j] : (_Float16)0;
            *(half8*)(&h1[row * 256 + p * 8]) = hv;
        }
    }
    __syncthreads();

    floatx4 acc[4][4] = {};
#pragma unroll
    for (int kk = 0; kk < 8; kk++) {
        if (kk < 7) {
#pragma unroll
            for (int nt = 0; nt < 4; nt++)
                bf_nxt[nt] = *(const half8*)(W2 + (size_t)(n0 + nt * 16 + mn) * 256 + (kk + 1) * 32 + q * 8);
        }
        half8 af[4];
#pragma unroll
        for (int mt = 0; mt < 4; mt++) {
            int r = mt * 16 + mn;
            int c = kk * 4 + q;
            int p = (c & ~7) | ((c ^ r) & 7);
            af[mt] = *(const half8*)(&h1[r * 256 + p * 8]);
        }
#pragma unroll
        for (int mt = 0; mt < 4; mt++)
#pragma unroll
            for (int nt = 0; nt < 4; nt++)
                acc[mt][nt] = __builtin_amdgcn_mfma_f32_16x16x32_f16(af[mt], bf_cur[nt], acc[mt][nt], 0, 0, 0);
        if (kk < 7) {
#pragma unroll
            for (int nt = 0; nt < 4; nt++) bf_cur[nt] = bf_nxt[nt];
        }
    }

#pragma unroll
    for (int nt = 0; nt < 4; nt++) {
        int col = n0 + nt * 16 + mn;
        float bias = b2[col];
        int curd = -1;
        float curv = 0.f;
#pragma unroll
        for (int mt = 0; mt < 4; mt++) {
#pragma unroll
            for (int r2 = 0; r2 < 4; r2++) {
                int er = mt * 16 + q * 4 + r2;  // monotone -> sorted dst runs merge
                int d = sd[er];
                float v = acc[mt][nt][r2] + bias;
                v = v > 0.f ? v : 0.f;
                if (d != curd) {
                    if (curd >= 0 && curv > 0.f)
                        atomicMax((unsigned int*)(agg + (size_t)curd * HH + col), __float_as_uint(curv));
                    curd = d;
                    curv = v;
                } else {
                    curv = fmaxf(curv, v);
                }
            }
        }
        if (curd >= 0 && curv > 0.f)
            atomicMax((unsigned int*)(agg + (size_t)curd * HH + col), __float_as_uint(curv));
    }
}

extern "C" void kernel_launch(void* const* d_in, const int* in_sizes, int n_in,
                              void* d_out, int out_size, void* d_ws, size_t ws_size,
                              hipStream_t stream) {
    const float* x = (const float*)d_in[0];
    const int* ei = (const int*)d_in[1];  // int32 per harness contract
    PrepArgs pa;
    const float* b0s[5];
    const float* b1s[5];
    for (int l = 0; l < 5; l++) {
        pa.w0[l] = (const float*)d_in[2 + 4 * l];
        b0s[l] = (const float*)d_in[3 + 4 * l];
        pa.w1[l] = (const float*)d_in[4 + 4 * l];
        b1s[l] = (const float*)d_in[5 + 4 * l];
    }

    int* ssrc = (int*)d_ws;                              // 256 KB
    int* sdst = ssrc + NE;                               // 256 KB
    int* counts = sdst + NE;                             // 4 KB
    int* cursor = counts + 1024;                         // 4 KB
    _Float16* node_ab = (_Float16*)(cursor + 1024);      // [1024][512] fp16, 1 MB
    float* aggA = (float*)(node_ab + 1024 * 512);        // [1000][256] fp32, 1 MB
    _Float16* wnode = (_Float16*)(aggA + NN * HH);       // 5 x [512][256] fp16, 1.25 MB
    _Float16* w2h = wnode + 5 * 512 * 256;               // 5 x [256][256] fp16, 0.63 MB

    hipMemsetAsync(counts, 0, 1024 * sizeof(int), stream);
    hipLaunchKernelGGL(hist_kernel, dim3((NE + 255) / 256), dim3(256), 0, stream, ei, counts);
    hipLaunchKernelGGL(scan_kernel, dim3(1), dim3(1024), 0, stream, counts, cursor);
    hipLaunchKernelGGL(scatter_kernel, dim3((NE + 255) / 256), dim3(256), 0, stream, ei, cursor, ssrc, sdst);
    hipLaunchKernelGGL(prep_weights, dim3(32, 5), dim3(256), 0, stream, pa, wnode, w2h);

    const float* cur = x;
    // Layers 0-3 write aggA, layer 4 writes d_out. aggA as both input and output
    // of a layer is safe: node_gemm fully consumes it before memset+edge_gemm
    // clobber it (stream-ordered).
    float* aggs[5] = {aggA, aggA, aggA, aggA, (float*)d_out};
    for (int l = 0; l < 5; l++) {
        if (l == 0)
            hipLaunchKernelGGL(node_gemm<4>, dim3(63, 4), dim3(256), 0, stream,
                               cur, wnode, b0s[0], node_ab);
        else
            hipLaunchKernelGGL(node_gemm<8>, dim3(63, 4), dim3(256), 0, stream,
                               cur, wnode + (size_t)l * 512 * 256, b0s[l], node_ab);
        hipMemsetAsync(aggs[l], 0, NN * HH * sizeof(float), stream);
        hipLaunchKernelGGL(edge_gemm, dim3(NE / 64), dim3(256), 0, stream,
                           node_ab, ssrc, sdst, w2h + (size_t)l * 256 * 256, b1s[l], aggs[l]);
        cur = aggs[l];
    }
}